// Round 9
// baseline (118.040 us; speedup 1.0000x reference)
//
#include <hip/hip_runtime.h>

#define B 16
#define C 128
#define NN 1024
#define KV 512
#define CHO 4

typedef _Float16 f16x8 __attribute__((ext_vector_type(8)));
typedef float f32x4 __attribute__((ext_vector_type(4)));

__device__ __forceinline__ unsigned short f2h(float v) {
  _Float16 h = (_Float16)v;
  return __builtin_bit_cast(unsigned short, h);
}
__device__ __forceinline__ unsigned int packh2(float a, float b) {
  return (unsigned int)f2h(a) | ((unsigned int)f2h(b) << 16);
}
__device__ __forceinline__ f16x8 ldcvt8(const float* __restrict__ p) {
  float4 a = *reinterpret_cast<const float4*>(p);
  float4 b = *reinterpret_cast<const float4*>(p + 4);
  f16x8 r;
  r[0] = (_Float16)a.x; r[1] = (_Float16)a.y; r[2] = (_Float16)a.z; r[3] = (_Float16)a.w;
  r[4] = (_Float16)b.x; r[5] = (_Float16)b.y; r[6] = (_Float16)b.z; r[7] = (_Float16)b.w;
  return r;
}
__device__ __forceinline__ f32x4 MFMA(f16x8 a, f16x8 b, f32x4 c) {
  return __builtin_amdgcn_mfma_f32_16x16x32_f16(a, b, c, 0, 0, 0);
}
// async global->LDS, 16B per lane; lds base must be wave-uniform (HW adds lane*16)
__device__ __forceinline__ void gld_lds16(const void* g, void* l) {
  __builtin_amdgcn_global_load_lds(
      (const __attribute__((address_space(1))) void*)g,
      (__attribute__((address_space(3))) void*)l, 16, 0, 0);
}

// ---------------- K1: projections via f16 MFMA (unchanged; verified)
__global__ __launch_bounds__(256, 4) void proj_kernel(
    const float* __restrict__ x, const float* __restrict__ Wq,
    const float* __restrict__ Wk, const float* __restrict__ Wv,
    unsigned short* __restrict__ fT, unsigned short* __restrict__ gT,
    unsigned short* __restrict__ hv)
{
  int wg = blockIdx.x;
  wg = (wg & 7) * 384 + (wg >> 3);      // XCD cluster
  const int b   = wg / 192;
  const int rem = wg % 192;
  const int rt  = rem % 12;
  const int n0  = (rem / 12) * 64;

  __shared__ __align__(16) unsigned short XT[64][136];   // XT[n][c] f16

  const int t = threadIdx.x;
  const int w = t >> 6, l = t & 63, lg = l >> 4, lm = l & 15;

  {
    const float* xb = x + (size_t)b * C * NN;
    #pragma unroll
    for (int i = 0; i < 8; ++i) {
      int flat = t + i * 256;
      int c  = flat >> 4;
      int ng = flat & 15;
      float4 v = *reinterpret_cast<const float4*>(xb + (size_t)c * NN + n0 + ng * 4);
      XT[ng * 4 + 0][c] = f2h(v.x);
      XT[ng * 4 + 1][c] = f2h(v.y);
      XT[ng * 4 + 2][c] = f2h(v.z);
      XT[ng * 4 + 3][c] = f2h(v.w);
    }
  }
  __syncthreads();

  if (rt < 4) {
    const float* Wsrc = (rt < 2) ? Wq : Wk;
    unsigned short* dst = (rt < 2) ? fT : gT;
    const int c0 = (rt & 1) * 64;
    const int r  = c0 + 16 * w + lm;
    f16x8 af[4];
    #pragma unroll
    for (int c4 = 0; c4 < 4; ++c4)
      af[c4] = ldcvt8(Wsrc + (size_t)r * C + c4 * 32 + lg * 8);
    #pragma unroll
    for (int nt4 = 0; nt4 < 4; ++nt4) {
      f32x4 acc = {0.f, 0.f, 0.f, 0.f};
      #pragma unroll
      for (int c4 = 0; c4 < 4; ++c4) {
        f16x8 xb = *reinterpret_cast<const f16x8*>(&XT[16 * nt4 + lm][c4 * 32 + lg * 8]);
        acc = MFMA(af[c4], xb, acc);
      }
      int n = n0 + 16 * nt4 + lm;
      ushort4 o = { f2h(acc[0]), f2h(acc[1]), f2h(acc[2]), f2h(acc[3]) };
      *reinterpret_cast<ushort4*>(dst + ((size_t)(b * NN) + n) * C + c0 + 16 * w + 4 * lg) = o;
    }
  } else {
    const int kk = (rt - 4) * 64 + 16 * w + lm;
    f16x8 wb[4];
    #pragma unroll
    for (int c4 = 0; c4 < 4; ++c4)
      wb[c4] = ldcvt8(Wv + (size_t)kk * C + c4 * 32 + lg * 8);
    #pragma unroll
    for (int nt4 = 0; nt4 < 4; ++nt4) {
      f32x4 acc = {0.f, 0.f, 0.f, 0.f};
      #pragma unroll
      for (int c4 = 0; c4 < 4; ++c4) {
        f16x8 xa = *reinterpret_cast<const f16x8*>(&XT[16 * nt4 + lm][c4 * 32 + lg * 8]);
        acc = MFMA(xa, wb[c4], acc);
      }
      ushort4 o = { f2h(acc[0]), f2h(acc[1]), f2h(acc[2]), f2h(acc[3]) };
      *reinterpret_cast<ushort4*>(hv + ((size_t)(b * KV) + kk) * NN + n0 + 16 * nt4 + 4 * lg) = o;
    }
  }
}

// ---------------- K2: MFMA flash attention (R5 skeleton + async K-staging)
// 4 waves, 64 m-cols, 16 chunks of 64 n, parity P, 1 barrier/chunk.
// K tile [64n][128c] staged in LDS via global_load_lds (dbuf, XOR-swizzled);
// V loads register-batched (one waitcnt), issued under softmax+barrier.
__global__ __launch_bounds__(256, 2) void attn_kernel(
    const unsigned short* __restrict__ fT, const unsigned short* __restrict__ gT,
    const unsigned short* __restrict__ hv, const float* __restrict__ gamma,
    const float* __restrict__ mask, float* __restrict__ out)
{
  int wg = blockIdx.x;
  wg = (wg & 7) * 32 + (wg >> 3);       // XCD cluster: 2 batches per XCD chunk
  const int b  = wg >> 4;
  const int m0 = (wg & 15) * 64;

  const int t = threadIdx.x;
  const int w = t >> 6, l = t & 63, lg = l >> 4, lm = l & 15;

  __shared__ __align__(16) unsigned short Klds[2][64][128];  // 2 x 16KB, swizzled
  __shared__ __align__(16) unsigned short P_lds[2][64][72];  // [par][m][n] f16
  __shared__ float resc_s[2][64];
  __shared__ float lsum_s[64];

  // Q frags: B operand, lane holds gT[m0+16w+lm][c4*32+8lg+i]
  f16x8 qf[4];
  {
    const unsigned short* qp = gT + ((size_t)(b * NN) + m0 + 16 * w + lm) * C + lg * 8;
    #pragma unroll
    for (int c4 = 0; c4 < 4; ++c4)
      qf[c4] = *reinterpret_cast<const f16x8*>(qp + c4 * 32);
  }

  f32x4 acc[8][4];  // [kt][mt]: k = 128w+16kt+4lg+reg, m = m0+16mt+lm
  #pragma unroll
  for (int kt = 0; kt < 8; ++kt)
    #pragma unroll
    for (int mt = 0; mt < 4; ++mt)
      acc[kt][mt] = (f32x4){0.f, 0.f, 0.f, 0.f};

  float M = -3.0e38f, Lpart = 0.f;

  const char* fTb = (const char*)(fT + (size_t)(b * NN) * C);   // byte base, row stride 256B
  const unsigned short* vp = hv + ((size_t)(b * KV) + 128 * w + lm) * NN + lg * 8;

  // ---- prologue: stage K chunk 0 into Klds[0] (swizzled source, linear dest)
  #pragma unroll
  for (int i = 0; i < 4; ++i) {
    int slot = 4 * i + w;                     // wave-uniform
    int row  = slot * 4 + (l >> 4);
    int colb = (l & 15) * 16;
    gld_lds16(fTb + (size_t)row * 256 + (colb ^ ((row & 7) << 4)),
              (char*)&Klds[0][0][0] + slot * 1024);
  }
  __syncthreads();   // drain staging

  #pragma unroll 1
  for (int it = 0; it < 16; ++it) {
    const int cur = it & 1, nxt = cur ^ 1;
    const int n0  = it * 64;
    const int n1  = ((it + 1) & 15) * 64;     // wraps harmlessly at it=15

    // a) issue async staging of K(it+1) -> Klds[nxt] (drained by this body's barrier)
    #pragma unroll
    for (int i = 0; i < 4; ++i) {
      int slot = 4 * i + w;
      int row  = slot * 4 + (l >> 4);
      int colb = (l & 15) * 16;
      gld_lds16(fTb + (size_t)(n1 + row) * 256 + (colb ^ ((row & 7) << 4)),
                (char*)&Klds[nxt][0][0] + slot * 1024);
    }

    // b) QK^T from Klds[cur] (swizzled ds_read_b128), per-j batches of 4
    f32x4 st[4];
    #pragma unroll
    for (int j = 0; j < 4; ++j) st[j] = (f32x4){0.f, 0.f, 0.f, 0.f};
    #pragma unroll
    for (int j = 0; j < 4; ++j) {
      const char* kbase = (const char*)&Klds[cur][0][0] + (16 * j + lm) * 256;
      f16x8 kfr[4];
      #pragma unroll
      for (int c4 = 0; c4 < 4; ++c4)
        kfr[c4] = *reinterpret_cast<const f16x8*>(
            kbase + ((c4 * 64 + lg * 16) ^ ((lm & 7) << 4)));
      #pragma unroll
      for (int c4 = 0; c4 < 4; ++c4)
        st[j] = MFMA(kfr[c4], qf[c4], st[j]);
    }

    // c) batched V loads for chunk it (consumed after barrier; 1 waitcnt)
    f16x8 vf[8][2];
    #pragma unroll
    for (int kt = 0; kt < 8; ++kt) {
      vf[kt][0] = *reinterpret_cast<const f16x8*>(vp + (size_t)(16 * kt) * NN + n0);
      vf[kt][1] = *reinterpret_cast<const f16x8*>(vp + (size_t)(16 * kt) * NN + n0 + 32);
    }

    // d) online softmax over n (lane: n = n0+16j+4lg+reg, col m0+16w+lm)
    float cmax = -3.0e38f;
    #pragma unroll
    for (int j = 0; j < 4; ++j)
      cmax = fmaxf(cmax, fmaxf(fmaxf(st[j][0], st[j][1]), fmaxf(st[j][2], st[j][3])));
    cmax = fmaxf(cmax, __shfl_xor(cmax, 16, 64));
    cmax = fmaxf(cmax, __shfl_xor(cmax, 32, 64));
    float r = 1.0f;
    if (!__all(cmax <= M + 8.0f)) {       // T13 defer-rescale
      float newM = fmaxf(M, cmax);
      r = __expf(M - newM);
      M = newM;
      Lpart *= r;
    }
    float ls = 0.f;
    #pragma unroll
    for (int j = 0; j < 4; ++j) {        // exp in place (st becomes P)
      st[j][0] = __expf(st[j][0] - M);
      st[j][1] = __expf(st[j][1] - M);
      st[j][2] = __expf(st[j][2] - M);
      st[j][3] = __expf(st[j][3] - M);
      ls += (st[j][0] + st[j][1]) + (st[j][2] + st[j][3]);
    }
    Lpart += ls;
    if (lg == 0) resc_s[cur][16 * w + lm] = r;
    {
      unsigned short* prow = &P_lds[cur][16 * w + lm][0];
      #pragma unroll
      for (int j = 0; j < 4; ++j) {
        *(unsigned int*)(prow + 16 * j + 4 * lg)     = packh2(st[j][0], st[j][1]);
        *(unsigned int*)(prow + 16 * j + 4 * lg + 2) = packh2(st[j][2], st[j][3]);
      }
    }

    // e) the ONLY barrier per chunk (orders P, drains K staging)
    __syncthreads();

    // f) rescale + P^T frags + PV
    float rr0 = resc_s[cur][lm],      rr1 = resc_s[cur][16 + lm],
          rr2 = resc_s[cur][32 + lm], rr3 = resc_s[cur][48 + lm];
    if (!__all((rr0 == 1.f) & (rr1 == 1.f) & (rr2 == 1.f) & (rr3 == 1.f))) {
      #pragma unroll
      for (int kt = 0; kt < 8; ++kt) {
        acc[kt][0] *= rr0; acc[kt][1] *= rr1;
        acc[kt][2] *= rr2; acc[kt][3] *= rr3;
      }
    }
    f16x8 pt[4][2];
    #pragma unroll
    for (int mt = 0; mt < 4; ++mt) {
      pt[mt][0] = *reinterpret_cast<const f16x8*>(&P_lds[cur][16 * mt + lm][8 * lg]);
      pt[mt][1] = *reinterpret_cast<const f16x8*>(&P_lds[cur][16 * mt + lm][32 + 8 * lg]);
    }
    #pragma unroll
    for (int kt = 0; kt < 8; ++kt)
      #pragma unroll
      for (int mt = 0; mt < 4; ++mt) {
        acc[kt][mt] = MFMA(vf[kt][0], pt[mt][0], acc[kt][mt]);
        acc[kt][mt] = MFMA(vf[kt][1], pt[mt][1], acc[kt][mt]);
      }
    // no trailing barrier: next chunk writes the other parity buffers
  }

  // denominators
  float Lp = Lpart;
  Lp += __shfl_xor(Lp, 16, 64);
  Lp += __shfl_xor(Lp, 32, 64);
  if (lg == 0) lsum_s[16 * w + lm] = Lp;
  __syncthreads();

  const float gam = gamma[0];
  float scv[4] = { gam / lsum_s[lm],      gam / lsum_s[16 + lm],
                   gam / lsum_s[32 + lm], gam / lsum_s[48 + lm] };

  // out[b][oc][m][ch] + mask[oc][m][ch];  k = 128w+16kt+4lg+reg -> oc=k&127, ch=w
  #pragma unroll
  for (int kt = 0; kt < 8; ++kt) {
    #pragma unroll
    for (int mt = 0; mt < 4; ++mt) {
      int m = m0 + 16 * mt + lm;
      #pragma unroll
      for (int reg = 0; reg < 4; ++reg) {
        int oc = 16 * kt + 4 * lg + reg;
        float v = acc[kt][mt][reg] * scv[mt] + mask[((size_t)oc * NN + m) * CHO + w];
        out[(((size_t)(b * 128 + oc)) * NN + m) * CHO + w] = v;
      }
    }
  }
}

extern "C" void kernel_launch(void* const* d_in, const int* in_sizes, int n_in,
                              void* d_out, int out_size, void* d_ws, size_t ws_size,
                              hipStream_t stream) {
  const float* x     = (const float*)d_in[0];
  const float* Wq    = (const float*)d_in[1];
  const float* Wk    = (const float*)d_in[2];
  const float* Wv    = (const float*)d_in[3];
  const float* gamma = (const float*)d_in[4];
  const float* mask  = (const float*)d_in[5];
  float* out = (float*)d_out;

  unsigned short* fT = (unsigned short*)d_ws;                 // [B][NN][C]  f16
  unsigned short* gT = fT + (size_t)B * NN * C;               // [B][NN][C]  f16
  unsigned short* hv = gT + (size_t)B * NN * C;               // [B][KV][NN] f16

  proj_kernel<<<dim3(3072), 256, 0, stream>>>(x, Wq, Wk, Wv, fT, gT, hv);
  attn_kernel<<<dim3(256), 256, 0, stream>>>(fT, gT, hv, gamma, mask, out);
}